// Round 8
// baseline (3981.931 us; speedup 1.0000x reference)
//
#include <hip/hip_runtime.h>
#include <math.h>

#define S_LEN 1024
#define BATCH 2048
#define MTILE 8
#define HID   128
#define NBLK  (BATCH / MTILE)   // 256 blocks -> every CU active
#define INV2048 (1.0f / 2048.0f)

// ws layout, offsets in _Float16 elements. K-extended arrays are [128][160]:
// k<128 = real weights, k=128..130 = (bias, x0-coef, x1-coef), k=131..159 = 0.
#define H_M1H 0
#define H_M1L 20480
#define H_MSH 40960
#define H_MSL 61440
#define H_ASH 81920
#define H_ASL 102400
#define H_WMH 122880     // [128][128] WtauM[:,128:256] hi
#define H_WML 139264
#define H_WBH 155648     // [128][128] WtauAdp[:,128:256] hi
#define H_WBL 172032
#define OFF_PART_F 94208 // float index into ws for per-block partials [256]

typedef _Float16 half8 __attribute__((ext_vector_type(8)));
typedef _Float16 half4 __attribute__((ext_vector_type(4)));
typedef float floatx4 __attribute__((ext_vector_type(4)));

#define MFMA(a, b, c) __builtin_amdgcn_mfma_f32_16x16x32_f16((a), (b), (c), 0, 0, 0)

__device__ __forceinline__ void put_hl(_Float16* ws, int hiBase, int loBase,
                                       int idx, float v) {
  _Float16 hi = (_Float16)v;
  ws[hiBase + idx] = hi;
  ws[loBase + idx] = (_Float16)((v - (float)hi) * 2048.0f);
}

// ---- prep: fold dense->tau coupling + all per-h scalars into f16 hi/lo
// fragment-ready arrays. (unchanged from round 6)
__global__ __launch_bounds__(192) void prep(
    const float* __restrict__ W1x, const float* __restrict__ b1x,
    const float* __restrict__ WtauM, const float* __restrict__ btauM,
    const float* __restrict__ WtauAdp, const float* __restrict__ btauAdp,
    _Float16* __restrict__ ws) {
  const int h = blockIdx.x, k = threadIdx.x;
  if (k >= 160) return;
  if (k < 128) {
    float w1 = W1x[h * 130 + 2 + k];
    float s1 = 0.f, s2 = 0.f;
    for (int d = 0; d < 128; ++d) {
      float wd = W1x[d * 130 + 2 + k];
      s1 += WtauM[h * 256 + d] * wd;
      s2 += WtauAdp[h * 256 + d] * wd;
    }
    put_hl(ws, H_M1H, H_M1L, h * 160 + k, w1);
    put_hl(ws, H_MSH, H_MSL, h * 160 + k, s1);
    put_hl(ws, H_ASH, H_ASL, h * 160 + k, s2);
    put_hl(ws, H_WMH, H_WML, h * 128 + k, WtauM[h * 256 + 128 + k]);
    put_hl(ws, H_WBH, H_WBL, h * 128 + k, WtauAdp[h * 256 + 128 + k]);
  } else if (k < 131) {
    const int col = k - 128;   // 0: bias, 1: x0-coef, 2: x1-coef
    float m1v = (col == 0) ? b1x[h] : W1x[h * 130 + (col - 1)];
    float sm = 0.f, sa = 0.f;
    for (int d = 0; d < 128; ++d) {
      float cv = (col == 0) ? b1x[d] : W1x[d * 130 + (col - 1)];
      sm += WtauM[h * 256 + d] * cv;
      sa += WtauAdp[h * 256 + d] * cv;
    }
    if (col == 0) { sm += btauM[h]; sa += btauAdp[h]; }
    put_hl(ws, H_M1H, H_M1L, h * 160 + k, m1v);
    put_hl(ws, H_MSH, H_MSL, h * 160 + k, sm);
    put_hl(ws, H_ASH, H_ASL, h * 160 + k, sa);
  } else {
    put_hl(ws, H_M1H, H_M1L, h * 160 + k, 0.f);
    put_hl(ws, H_MSH, H_MSL, h * 160 + k, 0.f);
    put_hl(ws, H_ASH, H_ASL, h * 160 + k, 0.f);
  }
}

// State slabs: per k-chunk f, 1 KB holding B[n'][q'][j] at halves (n'*4+q')*8+j.
// n'=0..7: batch 0..7 HI values; n'=8..15: batch 0..7 LO values (x2048).
// spk slab: n'>=8 is ZERO (spk exact in f16) so lo-accumulators stay clean.
// Lane (c,q) reads halves (c*4+q)*8 -> lane-contiguous b128, conflict-free.
struct SLds {
  _Float16 spk[2][4][512];
  _Float16 bx[2][512];          // K-ext [1,x0,x1] operand, hi|lo packed
  _Float16 mem[2][4][512];
  _Float16 bbp[2][4][512];
  float red[8][8];
  float red2[8];
};

__global__ __launch_bounds__(512, 2) void snn_main(
    const float* __restrict__ x, const float* __restrict__ y,
    const float* __restrict__ h0m, const float* __restrict__ h0s,
    const float* __restrict__ h0b,
    const float* __restrict__ Wlin, const float* __restrict__ blin,
    const _Float16* __restrict__ W, float* __restrict__ wsout) {
  __shared__ SLds L;

  const int tid  = threadIdx.x;
  const int w    = tid >> 6;      // wave 0..7, owns h-slice [16w, 16w+16)
  const int lane = tid & 63;
  const int c    = lane & 15;     // A-frag m / B-frag n / C col
  const int q    = lane >> 4;
  const int bbase = blockIdx.x * MTILE;
  const bool act = (c < 8);       // cols 8..15 are lo-lanes (no real batch)

  // ---- Register-resident A-frag weights (MFMA-only -> AGPR side)
  half8 m1h[5], m1l[5], msh[5], msl[5], ash[5], asl[5];
  half8 wmh[4], wml[4], wbh[4], wbl[4];
  {
    const int hA = w * 16 + c;
#pragma unroll
    for (int f = 0; f < 5; ++f) {
      const int o = hA * 160 + f * 32 + q * 8;
      m1h[f] = *(const half8*)&W[H_M1H + o];
      m1l[f] = *(const half8*)&W[H_M1L + o];
      msh[f] = *(const half8*)&W[H_MSH + o];
      msl[f] = *(const half8*)&W[H_MSL + o];
      ash[f] = *(const half8*)&W[H_ASH + o];
      asl[f] = *(const half8*)&W[H_ASL + o];
    }
#pragma unroll
    for (int f = 0; f < 4; ++f) {
      const int o = hA * 128 + f * 32 + q * 8;
      wmh[f] = *(const half8*)&W[H_WMH + o];
      wml[f] = *(const half8*)&W[H_WML + o];
      wbh[f] = *(const half8*)&W[H_WBH + o];
      wbl[f] = *(const half8*)&W[H_WBL + o];
    }
  }

  // ---- Zero spk slabs (lo halves must stay 0) + bx slabs (q'>0 granules)
  {
    uint32_t* z = (uint32_t*)&L.spk[0][0][0];   // spk + bx contiguous: 2560 u32
#pragma unroll
    for (int j = 0; j < 5; ++j) z[tid + 512 * j] = 0;
  }

  // ---- Per-lane recurrent state (c<8 lanes): h = w*16 + q*4 + r, b = bbase+c
  float memv[4], spk[4], bb[4];
#pragma unroll
  for (int r = 0; r < 4; ++r) { memv[r] = 0.f; spk[r] = 0.f; bb[r] = 0.f; }
  if (act) {
#pragma unroll
    for (int r = 0; r < 4; ++r) {
      const int gi = (bbase + c) * HID + w * 16 + q * 4 + r;
      memv[r] = h0m[gi]; spk[r] = h0s[gi]; bb[r] = h0b[gi];
    }
  }
  __syncthreads();   // zeros visible before value writes

  // Write offsets (constant over t): chunk fW = w>>1,
  // granule q' = (w&1)*2 + (q>>1), j-base = (q&1)*4
  const int fW  = w >> 1;
  const int qp  = (w & 1) * 2 + (q >> 1);
  const int wiH = (c * 4 + qp) * 8 + (q & 1) * 4;          // hi half (n'=c)
  const int wiL = ((c + 8) * 4 + qp) * 8 + (q & 1) * 4;    // lo half (n'=c+8)
  const int ri  = (c * 4 + q) * 8;                          // read offset

  if (act) {   // initial state into buf 0 via the standard write path
    half4 ps, mh4, ml4, bh4, bl4;
#pragma unroll
    for (int r = 0; r < 4; ++r) {
      ps[r] = (_Float16)spk[r];
      float v = memv[r]; _Float16 hi = (_Float16)v;
      mh4[r] = hi; ml4[r] = (_Float16)((v - (float)hi) * 2048.0f);
      v = bb[r]; hi = (_Float16)v;
      bh4[r] = hi; bl4[r] = (_Float16)((v - (float)hi) * 2048.0f);
    }
    *(half4*)&L.spk[0][fW][wiH] = ps;
    *(half4*)&L.mem[0][fW][wiH] = mh4; *(half4*)&L.mem[0][fW][wiL] = ml4;
    *(half4*)&L.bbp[0][fW][wiH] = bh4; *(half4*)&L.bbp[0][fW][wiL] = bl4;
  }
  if (tid < 16) {  // stage bx[0] from x[0]
    float2 x0 = *(const float2*)&x[(size_t)(bbase + (tid & 7)) * 2];
    half8 v;
    if (tid < 8) {
      v = half8{(_Float16)1.0f, (_Float16)x0.x, (_Float16)x0.y, 0, 0, 0, 0, 0};
    } else {
      _Float16 xh0 = (_Float16)x0.x, xh1 = (_Float16)x0.y;
      v = half8{0, (_Float16)((x0.x - (float)xh0) * 2048.0f),
                   (_Float16)((x0.y - (float)xh1) * 2048.0f), 0, 0, 0, 0, 0};
    }
    *(half8*)&L.bx[0][tid * 32] = v;   // granule (n'=tid, q'=0)
  }
  __syncthreads();

#pragma unroll 1
  for (int t = 0; t < S_LEN; ++t) {
    const int p = t & 1, pn = p ^ 1;

    floatx4 d1 = {0.f,0.f,0.f,0.f}, d2 = {0.f,0.f,0.f,0.f};
    floatx4 m1 = {0.f,0.f,0.f,0.f}, m2 = {0.f,0.f,0.f,0.f};
    floatx4 a1 = {0.f,0.f,0.f,0.f}, a2 = {0.f,0.f,0.f,0.f};

#pragma unroll
    for (int f = 0; f < 4; ++f) {
      half8 S = *(const half8*)&L.spk[p][f][ri];   // [spk | 0]
      half8 M = *(const half8*)&L.mem[p][f][ri];   // [mh  | ml]
      half8 B = *(const half8*)&L.bbp[p][f][ri];   // [bh  | bl]
      d1 = MFMA(m1h[f], S, d1);
      d2 = MFMA(m1l[f], S, d2);
      m1 = MFMA(msh[f], S, m1);
      m1 = MFMA(wmh[f], M, m1);    // cols0-7: wmh*mh ; cols8-15: wmh*ml
      m2 = MFMA(msl[f], S, m2);
      m2 = MFMA(wml[f], M, m2);    // cols0-7: wml*mh ; cols8-15: lo*lo (junk)
      a1 = MFMA(ash[f], S, a1);
      a1 = MFMA(wbh[f], B, a1);
      a2 = MFMA(asl[f], S, a2);
      a2 = MFMA(wbl[f], B, a2);
    }
    {  // K-extension: bias + x coupling, hi|lo packed operand
      half8 E = *(const half8*)&L.bx[p][ri];
      d1 = MFMA(m1h[4], E, d1);
      d2 = MFMA(m1l[4], E, d2);
      m1 = MFMA(msh[4], E, m1);
      m2 = MFMA(msl[4], E, m2);
      a1 = MFMA(ash[4], E, a1);
      a2 = MFMA(asl[4], E, a2);
    }

    // Gather partner-lane lo-sums (all lanes active for shfl validity)
    floatx4 d1o, m1o, a1o;
#pragma unroll
    for (int r = 0; r < 4; ++r) {
      d1o[r] = __shfl_xor(d1[r], 8);
      m1o[r] = __shfl_xor(m1[r], 8);
      a1o[r] = __shfl_xor(a1[r], 8);
    }

    // ---- Elementwise update + packed slab writes (real-batch lanes only)
    if (act) {
      half4 ps, mh4, ml4, bh4, bl4;
#pragma unroll
      for (int r = 0; r < 4; ++r) {
        float den  = d1[r] + (d1o[r] + d2[r]) * INV2048;
        float preM = m1[r] + (m1o[r] + m2[r]) * INV2048;
        float preA = a1[r] + (a1o[r] + a2[r]) * INV2048;
        float tM = __builtin_amdgcn_rcpf(1.0f + __expf(-preM));
        float tA = __builtin_amdgcn_rcpf(1.0f + __expf(-preA));
        bb[r] = tA * bb[r] + (1.0f - tA) * spk[r];
        float Bth = 0.01f + 1.8f * bb[r];
        memv[r] = memv[r] * tM + (1.0f - tM) * den - Bth * spk[r];
        spk[r] = (memv[r] - Bth) > 0.0f ? 1.0f : 0.0f;
        ps[r] = (_Float16)spk[r];
        float v = memv[r]; _Float16 hi = (_Float16)v;
        mh4[r] = hi; ml4[r] = (_Float16)((v - (float)hi) * 2048.0f);
        v = bb[r]; hi = (_Float16)v;
        bh4[r] = hi; bl4[r] = (_Float16)((v - (float)hi) * 2048.0f);
      }
      *(half4*)&L.spk[pn][fW][wiH] = ps;
      *(half4*)&L.mem[pn][fW][wiH] = mh4; *(half4*)&L.mem[pn][fW][wiL] = ml4;
      *(half4*)&L.bbp[pn][fW][wiH] = bh4; *(half4*)&L.bbp[pn][fW][wiL] = bl4;
    }

    if (tid < 16) {   // stage next step's K-extension fragment
      const size_t tn = (t + 1 < S_LEN) ? (size_t)(t + 1) : (size_t)t;
      float2 xn = *(const float2*)&x[(tn * BATCH + bbase + (tid & 7)) * 2];
      half8 v;
      if (tid < 8) {
        v = half8{(_Float16)1.0f, (_Float16)xn.x, (_Float16)xn.y, 0, 0, 0, 0, 0};
      } else {
        _Float16 xh0 = (_Float16)xn.x, xh1 = (_Float16)xn.y;
        v = half8{0, (_Float16)((xn.x - (float)xh0) * 2048.0f),
                     (_Float16)((xn.y - (float)xh1) * 2048.0f), 0, 0, 0, 0, 0};
      }
      *(half8*)&L.bx[pn][tid * 32] = v;
    }
    __syncthreads();
  }

  // ---- Readout: out[b] = mem[b,:] @ Wlin + blin; per-block loss partial
  float part = 0.0f;
#pragma unroll
  for (int r = 0; r < 4; ++r)
    part += memv[r] * Wlin[w * 16 + q * 4 + r];
  part += __shfl_xor(part, 16);
  part += __shfl_xor(part, 32);   // sum over q (same c)
  if (lane < 8) L.red[w][c] = part;
  __syncthreads();
  if (tid < 8) {
    float s = 0.0f;
#pragma unroll
    for (int ww = 0; ww < 8; ++ww) s += L.red[ww][tid];
    float out = s + blin[0];
    float d = out - y[bbase + tid];
    L.red2[tid] = d * d;
  }
  __syncthreads();
  if (tid == 0) {
    float s = 0.0f;
#pragma unroll
    for (int m = 0; m < MTILE; ++m) s += L.red2[m];
    wsout[blockIdx.x] = s;
  }
}

__global__ __launch_bounds__(256) void final_reduce(const float* __restrict__ part,
                                                    float* __restrict__ out) {
  __shared__ float sh[256];
  int t = threadIdx.x;
  sh[t] = part[t];
  __syncthreads();
  for (int s = 128; s > 0; s >>= 1) {
    if (t < s) sh[t] += sh[t + s];
    __syncthreads();
  }
  if (t == 0) out[0] = sh[0] * (1.0f / (float)BATCH);
}

extern "C" void kernel_launch(void* const* d_in, const int* in_sizes, int n_in,
                              void* d_out, int out_size, void* d_ws, size_t ws_size,
                              hipStream_t stream) {
  const float* x       = (const float*)d_in[0];
  const float* y       = (const float*)d_in[1];
  const float* h0m     = (const float*)d_in[2];
  const float* h0s     = (const float*)d_in[3];
  const float* h0b     = (const float*)d_in[4];
  const float* W1x     = (const float*)d_in[5];
  const float* b1x     = (const float*)d_in[6];
  const float* WtauM   = (const float*)d_in[7];
  const float* btauM   = (const float*)d_in[8];
  const float* WtauAdp = (const float*)d_in[9];
  const float* btauAdp = (const float*)d_in[10];
  const float* Wlin    = (const float*)d_in[11];
  const float* blin    = (const float*)d_in[12];
  _Float16* wsf16 = (_Float16*)d_ws;
  float* wspart = (float*)d_ws + OFF_PART_F;

  prep<<<128, 192, 0, stream>>>(W1x, b1x, WtauM, btauM, WtauAdp, btauAdp, wsf16);
  snn_main<<<NBLK, 512, 0, stream>>>(x, y, h0m, h0s, h0b, Wlin, blin,
                                     wsf16, wspart);
  final_reduce<<<1, 256, 0, stream>>>(wspart, (float*)d_out);
}

// Round 9
// 2406.996 us; speedup vs baseline: 1.6543x; 1.6543x over previous
//
#include <hip/hip_runtime.h>
#include <math.h>

#define S_LEN 1024
#define BATCH 2048
#define MTILE 8
#define HID   128
#define NBLK  (BATCH / MTILE)   // 256 blocks -> every CU active
#define INV2048 (1.0f / 2048.0f)

// ws layout, offsets in _Float16 elements. K-extended arrays are [128][160]:
// k<128 = real weights, k=128..130 = (bias, x0-coef, x1-coef), k=131..159 = 0.
#define H_M1H 0
#define H_M1L 20480
#define H_MSH 40960
#define H_MSL 61440
#define H_ASH 81920
#define H_ASL 102400
#define H_WMH 122880     // [128][128] WtauM[:,128:256] hi
#define H_WML 139264
#define H_WBH 155648     // [128][128] WtauAdp[:,128:256] hi
#define H_WBL 172032
#define OFF_PART_F 94208 // float index into ws for per-block partials [256]

typedef _Float16 half8 __attribute__((ext_vector_type(8)));
typedef _Float16 half4 __attribute__((ext_vector_type(4)));
typedef float floatx4 __attribute__((ext_vector_type(4)));

#define MFMA(a, b, c) __builtin_amdgcn_mfma_f32_16x16x32_f16((a), (b), (c), 0, 0, 0)

__device__ __forceinline__ void put_hl(_Float16* ws, int hiBase, int loBase,
                                       int idx, float v) {
  _Float16 hi = (_Float16)v;
  ws[hiBase + idx] = hi;
  ws[loBase + idx] = (_Float16)((v - (float)hi) * 2048.0f);
}

// ---- prep: fold dense->tau coupling + all per-h scalars into f16 hi/lo
// fragment-ready arrays. (unchanged)
__global__ __launch_bounds__(192) void prep(
    const float* __restrict__ W1x, const float* __restrict__ b1x,
    const float* __restrict__ WtauM, const float* __restrict__ btauM,
    const float* __restrict__ WtauAdp, const float* __restrict__ btauAdp,
    _Float16* __restrict__ ws) {
  const int h = blockIdx.x, k = threadIdx.x;
  if (k >= 160) return;
  if (k < 128) {
    float w1 = W1x[h * 130 + 2 + k];
    float s1 = 0.f, s2 = 0.f;
    for (int d = 0; d < 128; ++d) {
      float wd = W1x[d * 130 + 2 + k];
      s1 += WtauM[h * 256 + d] * wd;
      s2 += WtauAdp[h * 256 + d] * wd;
    }
    put_hl(ws, H_M1H, H_M1L, h * 160 + k, w1);
    put_hl(ws, H_MSH, H_MSL, h * 160 + k, s1);
    put_hl(ws, H_ASH, H_ASL, h * 160 + k, s2);
    put_hl(ws, H_WMH, H_WML, h * 128 + k, WtauM[h * 256 + 128 + k]);
    put_hl(ws, H_WBH, H_WBL, h * 128 + k, WtauAdp[h * 256 + 128 + k]);
  } else if (k < 131) {
    const int col = k - 128;   // 0: bias, 1: x0-coef, 2: x1-coef
    float m1v = (col == 0) ? b1x[h] : W1x[h * 130 + (col - 1)];
    float sm = 0.f, sa = 0.f;
    for (int d = 0; d < 128; ++d) {
      float cv = (col == 0) ? b1x[d] : W1x[d * 130 + (col - 1)];
      sm += WtauM[h * 256 + d] * cv;
      sa += WtauAdp[h * 256 + d] * cv;
    }
    if (col == 0) { sm += btauM[h]; sa += btauAdp[h]; }
    put_hl(ws, H_M1H, H_M1L, h * 160 + k, m1v);
    put_hl(ws, H_MSH, H_MSL, h * 160 + k, sm);
    put_hl(ws, H_ASH, H_ASL, h * 160 + k, sa);
  } else {
    put_hl(ws, H_M1H, H_M1L, h * 160 + k, 0.f);
    put_hl(ws, H_MSH, H_MSL, h * 160 + k, 0.f);
    put_hl(ws, H_ASH, H_ASL, h * 160 + k, 0.f);
  }
}

// State slabs: per k-chunk f, 1 KB; half-index (q'*16 + n')*8 + j holds
// B[k=f*32+q'*8+j][n']. n'=0..7: batch HI; n'=8..15: batch LO (x2048);
// spk n'>=8 stays zero. Lane (c,q) reads half-index (q*16+c)*8 = lane*8
// -> identity lane-contiguous b128 (m97 fast path, conflict-free).
struct SLds {
  _Float16 spk[2][4][512];
  _Float16 bx[2][512];          // K-ext [1,x0,x1] operand, hi|lo packed
  _Float16 mem[2][4][512];
  _Float16 bbp[2][4][512];
  float red[8][8];
  float red2[8];
};

__global__ __launch_bounds__(512, 2) void snn_main(
    const float* __restrict__ x, const float* __restrict__ y,
    const float* __restrict__ h0m, const float* __restrict__ h0s,
    const float* __restrict__ h0b,
    const float* __restrict__ Wlin, const float* __restrict__ blin,
    const _Float16* __restrict__ W, float* __restrict__ wsout) {
  __shared__ SLds L;

  const int tid  = threadIdx.x;
  const int w    = tid >> 6;      // wave 0..7, owns h-slice [16w, 16w+16)
  const int lane = tid & 63;
  const int c    = lane & 15;     // A-frag m / B-frag n / C col
  const int q    = lane >> 4;
  const int bbase = blockIdx.x * MTILE;
  const bool act = (c < 8);       // cols 8..15 are lo-lanes (no real batch)

  // ---- Register-resident A-frag weights (MFMA-only -> AGPR side)
  half8 m1h[5], m1l[5], msh[5], msl[5], ash[5], asl[5];
  half8 wmh[4], wml[4], wbh[4], wbl[4];
  {
    const int hA = w * 16 + c;
#pragma unroll
    for (int f = 0; f < 5; ++f) {
      const int o = hA * 160 + f * 32 + q * 8;
      m1h[f] = *(const half8*)&W[H_M1H + o];
      m1l[f] = *(const half8*)&W[H_M1L + o];
      msh[f] = *(const half8*)&W[H_MSH + o];
      msl[f] = *(const half8*)&W[H_MSL + o];
      ash[f] = *(const half8*)&W[H_ASH + o];
      asl[f] = *(const half8*)&W[H_ASL + o];
    }
#pragma unroll
    for (int f = 0; f < 4; ++f) {
      const int o = hA * 128 + f * 32 + q * 8;
      wmh[f] = *(const half8*)&W[H_WMH + o];
      wml[f] = *(const half8*)&W[H_WML + o];
      wbh[f] = *(const half8*)&W[H_WBH + o];
      wbl[f] = *(const half8*)&W[H_WBL + o];
    }
  }

  // ---- Zero spk (both bufs; lo halves must stay 0) + bx slabs.
  // spk[2][4][512] (2048 u32) + bx[2][512] (512 u32) are contiguous.
  {
    uint32_t* z = (uint32_t*)&L.spk[0][0][0];
#pragma unroll
    for (int j = 0; j < 5; ++j) z[tid + 512 * j] = 0;
  }

  // ---- Per-lane recurrent state (act lanes): h = w*16 + q*4 + r, b = bbase+c
  float memv[4], spk[4], bb[4];
#pragma unroll
  for (int r = 0; r < 4; ++r) { memv[r] = 0.f; spk[r] = 0.f; bb[r] = 0.f; }
  if (act) {
#pragma unroll
    for (int r = 0; r < 4; ++r) {
      const int gi = (bbase + c) * HID + w * 16 + q * 4 + r;
      memv[r] = h0m[gi]; spk[r] = h0s[gi]; bb[r] = h0b[gi];
    }
  }
  __syncthreads();   // zeros visible before value writes

  // State value (h = w*16+q*4+r) enters GEMM2 as B[k=h][n]:
  // chunk fW = w>>1, granule qp = (w&1)*2 + (q>>1), j = (q&1)*4 + r.
  const int fW  = w >> 1;
  const int qp  = (w & 1) * 2 + (q >> 1);
  const int wiH = (qp * 16 + c) * 8 + (q & 1) * 4;        // hi half (n'=c)
  const int wiL = (qp * 16 + c + 8) * 8 + (q & 1) * 4;    // lo half (n'=c+8)
  const int ri  = lane * 8;                                // identity read

  if (act) {   // initial state into buf 0 via the standard write path
    half4 ps, mh4, ml4, bh4, bl4;
#pragma unroll
    for (int r = 0; r < 4; ++r) {
      ps[r] = (_Float16)spk[r];
      float v = memv[r]; _Float16 hi = (_Float16)v;
      mh4[r] = hi; ml4[r] = (_Float16)((v - (float)hi) * 2048.0f);
      v = bb[r]; hi = (_Float16)v;
      bh4[r] = hi; bl4[r] = (_Float16)((v - (float)hi) * 2048.0f);
    }
    *(half4*)&L.spk[0][fW][wiH] = ps;
    *(half4*)&L.mem[0][fW][wiH] = mh4; *(half4*)&L.mem[0][fW][wiL] = ml4;
    *(half4*)&L.bbp[0][fW][wiH] = bh4; *(half4*)&L.bbp[0][fW][wiL] = bl4;
  }
  if (tid < 16) {  // stage bx[0]: granule q'=0, n'=tid -> half-index tid*8
    float2 x0 = *(const float2*)&x[(size_t)(bbase + (tid & 7)) * 2];
    half8 v;
    if (tid < 8) {
      v = half8{(_Float16)1.0f, (_Float16)x0.x, (_Float16)x0.y, 0, 0, 0, 0, 0};
    } else {
      _Float16 xh0 = (_Float16)x0.x, xh1 = (_Float16)x0.y;
      v = half8{0, (_Float16)((x0.x - (float)xh0) * 2048.0f),
                   (_Float16)((x0.y - (float)xh1) * 2048.0f), 0, 0, 0, 0, 0};
    }
    *(half8*)&L.bx[0][tid * 8] = v;
  }
  __syncthreads();

#pragma unroll 1
  for (int t = 0; t < S_LEN; ++t) {
    const int p = t & 1, pn = p ^ 1;

    floatx4 d1 = {0.f,0.f,0.f,0.f}, d2 = {0.f,0.f,0.f,0.f};
    floatx4 m1 = {0.f,0.f,0.f,0.f}, m2 = {0.f,0.f,0.f,0.f};
    floatx4 a1 = {0.f,0.f,0.f,0.f}, a2 = {0.f,0.f,0.f,0.f};

#pragma unroll
    for (int f = 0; f < 4; ++f) {
      half8 S = *(const half8*)&L.spk[p][f][ri];   // [spk | 0]
      half8 M = *(const half8*)&L.mem[p][f][ri];   // [mh  | ml]
      half8 B = *(const half8*)&L.bbp[p][f][ri];   // [bh  | bl]
      d1 = MFMA(m1h[f], S, d1);
      d2 = MFMA(m1l[f], S, d2);
      m1 = MFMA(msh[f], S, m1);
      m1 = MFMA(wmh[f], M, m1);    // cols0-7: wmh*mh ; cols8-15: wmh*ml
      m2 = MFMA(msl[f], S, m2);
      m2 = MFMA(wml[f], M, m2);    // cols0-7: wml*mh ; cols8-15: junk
      a1 = MFMA(ash[f], S, a1);
      a1 = MFMA(wbh[f], B, a1);
      a2 = MFMA(asl[f], S, a2);
      a2 = MFMA(wbl[f], B, a2);
    }
    {  // K-extension: bias + x coupling, hi|lo packed operand
      half8 E = *(const half8*)&L.bx[p][ri];
      d1 = MFMA(m1h[4], E, d1);
      d2 = MFMA(m1l[4], E, d2);
      m1 = MFMA(msh[4], E, m1);
      m2 = MFMA(msl[4], E, m2);
      a1 = MFMA(ash[4], E, a1);
      a2 = MFMA(asl[4], E, a2);
    }

    // Fold partner-lane lo-sums straight into the lo accumulators
#pragma unroll
    for (int r = 0; r < 4; ++r) {
      d2[r] += __shfl_xor(d1[r], 8);
      m2[r] += __shfl_xor(m1[r], 8);
      a2[r] += __shfl_xor(a1[r], 8);
    }

    // ---- Elementwise update (all lanes; junk in c>=8 stays private)
    half4 ps, mh4, ml4, bh4, bl4;
#pragma unroll
    for (int r = 0; r < 4; ++r) {
      float den  = d1[r] + d2[r] * INV2048;
      float preM = m1[r] + m2[r] * INV2048;
      float preA = a1[r] + a2[r] * INV2048;
      float tM = __builtin_amdgcn_rcpf(1.0f + __expf(-preM));
      float tA = __builtin_amdgcn_rcpf(1.0f + __expf(-preA));
      bb[r] = tA * bb[r] + (1.0f - tA) * spk[r];
      float Bth = 0.01f + 1.8f * bb[r];
      memv[r] = memv[r] * tM + (1.0f - tM) * den - Bth * spk[r];
      spk[r] = (memv[r] - Bth) > 0.0f ? 1.0f : 0.0f;
      ps[r] = (_Float16)spk[r];
      float v = memv[r]; _Float16 hi = (_Float16)v;
      mh4[r] = hi; ml4[r] = (_Float16)((v - (float)hi) * 2048.0f);
      v = bb[r]; hi = (_Float16)v;
      bh4[r] = hi; bl4[r] = (_Float16)((v - (float)hi) * 2048.0f);
    }
    if (act) {   // guarded stores only
      *(half4*)&L.spk[pn][fW][wiH] = ps;
      *(half4*)&L.mem[pn][fW][wiH] = mh4; *(half4*)&L.mem[pn][fW][wiL] = ml4;
      *(half4*)&L.bbp[pn][fW][wiH] = bh4; *(half4*)&L.bbp[pn][fW][wiL] = bl4;
    }

    if (tid < 16) {   // stage next step's K-extension fragment
      const size_t tn = (t + 1 < S_LEN) ? (size_t)(t + 1) : (size_t)t;
      float2 xn = *(const float2*)&x[(tn * BATCH + bbase + (tid & 7)) * 2];
      half8 v;
      if (tid < 8) {
        v = half8{(_Float16)1.0f, (_Float16)xn.x, (_Float16)xn.y, 0, 0, 0, 0, 0};
      } else {
        _Float16 xh0 = (_Float16)xn.x, xh1 = (_Float16)xn.y;
        v = half8{0, (_Float16)((xn.x - (float)xh0) * 2048.0f),
                     (_Float16)((xn.y - (float)xh1) * 2048.0f), 0, 0, 0, 0, 0};
      }
      *(half8*)&L.bx[pn][tid * 8] = v;
    }
    __syncthreads();
  }

  // ---- Readout: out[b] = mem[b,:] @ Wlin + blin; per-block loss partial
  float part = 0.0f;
#pragma unroll
  for (int r = 0; r < 4; ++r)
    part += memv[r] * Wlin[w * 16 + q * 4 + r];
  part += __shfl_xor(part, 16);
  part += __shfl_xor(part, 32);   // sum over q (same c)
  if (lane < 8) L.red[w][c] = part;
  __syncthreads();
  if (tid < 8) {
    float s = 0.0f;
#pragma unroll
    for (int ww = 0; ww < 8; ++ww) s += L.red[ww][tid];
    float out = s + blin[0];
    float d = out - y[bbase + tid];
    L.red2[tid] = d * d;
  }
  __syncthreads();
  if (tid == 0) {
    float s = 0.0f;
#pragma unroll
    for (int m = 0; m < MTILE; ++m) s += L.red2[m];
    wsout[blockIdx.x] = s;
  }
}

__global__ __launch_bounds__(256) void final_reduce(const float* __restrict__ part,
                                                    float* __restrict__ out) {
  __shared__ float sh[256];
  int t = threadIdx.x;
  sh[t] = part[t];
  __syncthreads();
  for (int s = 128; s > 0; s >>= 1) {
    if (t < s) sh[t] += sh[t + s];
    __syncthreads();
  }
  if (t == 0) out[0] = sh[0] * (1.0f / (float)BATCH);
}

extern "C" void kernel_launch(void* const* d_in, const int* in_sizes, int n_in,
                              void* d_out, int out_size, void* d_ws, size_t ws_size,
                              hipStream_t stream) {
  const float* x       = (const float*)d_in[0];
  const float* y       = (const float*)d_in[1];
  const float* h0m     = (const float*)d_in[2];
  const float* h0s     = (const float*)d_in[3];
  const float* h0b     = (const float*)d_in[4];
  const float* W1x     = (const float*)d_in[5];
  const float* b1x     = (const float*)d_in[6];
  const float* WtauM   = (const float*)d_in[7];
  const float* btauM   = (const float*)d_in[8];
  const float* WtauAdp = (const float*)d_in[9];
  const float* btauAdp = (const float*)d_in[10];
  const float* Wlin    = (const float*)d_in[11];
  const float* blin    = (const float*)d_in[12];
  _Float16* wsf16 = (_Float16*)d_ws;
  float* wspart = (float*)d_ws + OFF_PART_F;

  prep<<<128, 192, 0, stream>>>(W1x, b1x, WtauM, btauM, WtauAdp, btauAdp, wsf16);
  snn_main<<<NBLK, 512, 0, stream>>>(x, y, h0m, h0s, h0b, Wlin, blin,
                                     wsf16, wspart);
  final_reduce<<<1, 256, 0, stream>>>(wspart, (float*)d_out);
}